// Round 6
// baseline (624.064 us; speedup 1.0000x reference)
//
#include <hip/hip_runtime.h>
#include <hip/hip_bf16.h>
#include <cstdint>
#include <cstddef>

#define B_ 4
#define D_ 256
#define N_ 4096
#define N1 4097
#define MARGIN_ 0.5f
#define MAXD_ 10000.0f
#define BIGV_ 1000000000.0f
#define QSCALE 63.5f
#define QINV (4.0f / 254.0f)

typedef short s8v __attribute__((ext_vector_type(8)));
typedef float f4v __attribute__((ext_vector_type(4)));

// Order-preserving float <-> uint encoding so atomicMax/atomicMin on uint == on float.
__device__ __forceinline__ unsigned enc_f(float f) {
    unsigned u = __float_as_uint(f);
    return (u & 0x80000000u) ? ~u : (u | 0x80000000u);
}
__device__ __forceinline__ float dec_f(unsigned e) {
    return (e & 0x80000000u) ? __uint_as_float(e & 0x7FFFFFFFu) : __uint_as_float(~e);
}

__device__ __forceinline__ void async_copy16(__hip_bfloat16* lds, const __hip_bfloat16* g) {
    __builtin_amdgcn_global_load_lds(
        (const __attribute__((address_space(1))) void*)g,
        (__attribute__((address_space(3))) void*)lds, 16, 0, 0);
}

// ---------------- transpose+convert: (B,D,N) f32 -> (B,N,D) bf16, both descs ----------------
__global__ __launch_bounds__(256) void transpose_k(const float* __restrict__ src0,
                                                   const float* __restrict__ src1,
                                                   __hip_bfloat16* __restrict__ dst0,
                                                   __hip_bfloat16* __restrict__ dst1) {
    __shared__ float tile[64][65];
    int z = blockIdx.z;
    int b = z & 3;
    const float* src = (z < 4) ? src0 : src1;
    __hip_bfloat16* dst = (z < 4) ? dst0 : dst1;
    int i0 = blockIdx.x * 64;   // n-dim
    int k0 = blockIdx.y * 64;   // d-dim
    int tx = threadIdx.x;       // 0..63
    int ty = threadIdx.y;       // 0..3
    const float* s = src + ((size_t)b * D_ + k0) * N_ + i0;
#pragma unroll
    for (int r = 0; r < 16; ++r) {
        int kk = ty + 4 * r;
        tile[kk][tx] = s[(size_t)kk * N_ + tx];
    }
    __syncthreads();
    __hip_bfloat16* d = dst + ((size_t)b * N_ + i0) * D_ + k0;
#pragma unroll
    for (int r = 0; r < 16; ++r) {
        int ii = ty + 4 * r;
        d[(size_t)ii * D_ + tx] = __float2bfloat16(tile[tx][ii]);
    }
}

// ---------------- mask precompute (+ init of pos/mn arrays) ----------------
// mu[b][i][g] (ushort): low byte = match bits for cols 8g..8g+7 (ov>0.3),
//                       high byte = unmatch bits (ov<=0).
__global__ __launch_bounds__(256) void mask_k(const float* __restrict__ mat,
                                              unsigned short* __restrict__ mu,
                                              unsigned* __restrict__ initp) {
    int b = blockIdx.y;
    size_t t = (size_t)blockIdx.x * 256 + threadIdx.x;   // ushort index within batch
    if (b == 0 && blockIdx.x < 256) {
        int i = blockIdx.x * 256 + threadIdx.x;
        initp[i] = (i < 2 * B_ * N_) ? 0u : 0xFFFFFFFFu;
    }
    int i = (int)(t >> 9);          // row
    int g = (int)(t & 511);         // 8-col group
    const float* row = mat + (size_t)b * N1 * N1 + (size_t)i * N1 + g * 8;
    unsigned m = 0, u = 0;
#pragma unroll
    for (int k = 0; k < 8; ++k) {
        float v = row[k];
        m |= (v > 0.3f ? 1u : 0u) << k;
        u |= (v <= 0.0f ? 1u : 0u) << k;
    }
    mu[(size_t)b * N_ * 512 + t] = (unsigned short)(m | (u << 8));
}

// ---------------- persistent-A GEMM: pos maxes + u8 neg materialization ----------------
// Block: 512 threads (8 waves), 256 rows (i) x 512 cols (j-span); wave-tile 32x64.
// A-fragments (full K=256) in registers (staged via LDS in two 64 KB halves);
// B double-buffered through 2x32 KB LDS. Column relabel: j = jb + 4r + nj.
// pos1 accumulated in LDS (sCol), flushed once per block -> kills the per-jt
// same-address global-atomic serialization that bound R2..R5.
__global__ __launch_bounds__(512, 4) void gemm_k(const __hip_bfloat16* __restrict__ At,
                                                 const __hip_bfloat16* __restrict__ Bt,
                                                 const unsigned short* __restrict__ mu,
                                                 unsigned* __restrict__ pos0e,
                                                 unsigned* __restrict__ pos1e,
                                                 unsigned char* __restrict__ neg) {
    __shared__ __align__(16) __hip_bfloat16 Bs[2][64 * 256];   // 64 KB (also A staging)
    __shared__ unsigned sCol[512];

    const int b = blockIdx.z;
    const int i0 = blockIdx.y * 256;
    const int jg0 = blockIdx.x * 512;
    const int tid = threadIdx.x;
    const int lane = tid & 63;
    const int w = tid >> 6;         // 0..7
    const int r = lane & 15;
    const int q = lane >> 4;
    const int rl2 = lane >> 5;      // 0..1 row within 2-row staging granule
    const int ss = lane & 31;       // 16B slot within row

    sCol[tid] = 0u;                 // enc-space minimum

    __hip_bfloat16* BsF = &Bs[0][0];
    const __hip_bfloat16* Ab = At + ((size_t)b * N_ + i0) * D_;

    s8v af[2][8];
#pragma unroll
    for (int half = 0; half < 2; ++half) {
        // stage rows half*128 .. half*128+127 (64 KB, XOR-swizzled by row&7)
#pragma unroll
        for (int c = 0; c < 8; ++c) {
            int idx = w * 8 + c;            // 0..63, 1 KB granule each
            int rh = 2 * idx + rl2;         // 0..127
            int row = half * 128 + rh;
            async_copy16(BsF + idx * 512, Ab + (size_t)row * D_ + (ss ^ (rh & 7)) * 8);
        }
        __syncthreads();
        if ((w >> 2) == half) {
#pragma unroll
            for (int mi = 0; mi < 2; ++mi) {
                int row = w * 32 + mi * 16 + r;
                int rloc = row & 127;
#pragma unroll
                for (int s = 0; s < 8; ++s)
                    af[mi][s] = *(const s8v*)(BsF + rloc * 256 + (((s * 4 + q) ^ (row & 7)) * 8));
            }
        }
        __syncthreads();
    }

    // ---- stage B tile 0 (swizzle key (row>>2)&7 to match 4r+nj frag reads) ----
    {
        const __hip_bfloat16* Bb = Bt + ((size_t)b * N_ + jg0) * D_;
#pragma unroll
        for (int c = 0; c < 4; ++c) {
            int idx = w * 4 + c;            // 0..31
            int row = 2 * idx + rl2;        // 0..63
            async_copy16(&Bs[0][idx * 512], Bb + (size_t)row * D_ + (ss ^ ((row >> 2) & 7)) * 8);
        }
    }

    const unsigned short* mub = mu + ((size_t)b * N_ + i0) * 512;
    unsigned char* negb = neg + ((size_t)b * N_ + i0) * (size_t)N_;
    const int shn = 4 * (r & 1);

    float rowmax[8];
#pragma unroll
    for (int t = 0; t < 8; ++t) rowmax[t] = -BIGV_;

    for (int jt = 0; jt < 8; ++jt) {
        const int d = jt & 1;
        const int jb = jg0 + jt * 64;
        __syncthreads();                    // B[jt] staged; prior-buf reads done
        if (jt < 7) {                       // prefetch next j-subtile
            const __hip_bfloat16* Bb = Bt + ((size_t)b * N_ + jb + 64) * D_;
#pragma unroll
            for (int c = 0; c < 4; ++c) {
                int idx = w * 4 + c;
                int row = 2 * idx + rl2;
                async_copy16(&Bs[d ^ 1][idx * 512], Bb + (size_t)row * D_ + (ss ^ ((row >> 2) & 7)) * 8);
            }
        }
        // mask bits for this subtile (independent loads — hidden under MFMA)
        unsigned muv[8];
#pragma unroll
        for (int mi = 0; mi < 2; ++mi)
#pragma unroll
            for (int rr = 0; rr < 4; ++rr) {
                int il = w * 32 + mi * 16 + q * 4 + rr;
                muv[mi * 4 + rr] = mub[(size_t)il * 512 + (jb >> 3) + (r >> 1)];
            }

        f4v acc[2][4];
#pragma unroll
        for (int mi = 0; mi < 2; ++mi)
#pragma unroll
            for (int nj = 0; nj < 4; ++nj) acc[mi][nj] = (f4v){0.f, 0.f, 0.f, 0.f};

#pragma unroll
        for (int s = 0; s < 8; ++s) {
            s8v bf[4];
#pragma unroll
            for (int nj = 0; nj < 4; ++nj) {
                int rl = 4 * r + nj;
                bf[nj] = *(const s8v*)(&Bs[d][rl * 256 + (((s * 4 + q) ^ (r & 7)) * 8)]);
            }
#pragma unroll
            for (int mi = 0; mi < 2; ++mi)
#pragma unroll
                for (int nj = 0; nj < 4; ++nj)
                    acc[mi][nj] = __builtin_amdgcn_mfma_f32_16x16x32_bf16(af[mi][s], bf[nj], acc[mi][nj], 0, 0, 0);
        }

        // ---- epilogue for this 256x64 j-subtile ----
        float colmax[4] = {-BIGV_, -BIGV_, -BIGV_, -BIGV_};
#pragma unroll
        for (int mi = 0; mi < 2; ++mi) {
#pragma unroll
            for (int rr = 0; rr < 4; ++rr) {
                int il = w * 32 + mi * 16 + q * 4 + rr;
                unsigned v = muv[mi * 4 + rr];
                unsigned packed = 0;
#pragma unroll
                for (int nj = 0; nj < 4; ++nj) {
                    bool is_m = (v >> (shn + nj)) & 1;
                    bool is_u = (v >> (8 + shn + nj)) & 1;
                    float Dv = 2.0f - 2.0f * acc[mi][nj][rr];
                    float dp = is_m ? Dv : 0.0f;
                    rowmax[mi * 4 + rr] = fmaxf(rowmax[mi * 4 + rr], dp);
                    colmax[nj] = fmaxf(colmax[nj], dp);
                    unsigned qv = is_u
                        ? (unsigned)(fminf(fmaxf(Dv, 0.0f), 4.0f) * QSCALE + 0.5f)
                        : 255u;
                    packed |= qv << (nj * 8);
                }
                *(unsigned*)&negb[(size_t)il * N_ + jb + 4 * r] = packed;
            }
        }
        // fold 4 q-groups, then one LDS atomic per column (local, cheap)
#pragma unroll
        for (int nj = 0; nj < 4; ++nj) {
            float vv = colmax[nj];
            vv = fmaxf(vv, __shfl_xor(vv, 16, 64));
            vv = fmaxf(vv, __shfl_xor(vv, 32, 64));
            if (q == 0) atomicMax(&sCol[jt * 64 + 4 * r + nj], enc_f(vv));
        }
    }

    // ---- row maxes -> pos0 (one global atomic per row per block) ----
#pragma unroll
    for (int t = 0; t < 8; ++t) {
        float vv = rowmax[t];
#pragma unroll
        for (int m = 1; m < 16; m <<= 1) vv = fmaxf(vv, __shfl_xor(vv, m, 64));
        if (r == 0) {
            int row = w * 32 + (t >> 2) * 16 + q * 4 + (t & 3);
            atomicMax(&pos0e[b * N_ + i0 + row], enc_f(vv));
        }
    }
    // ---- col maxes -> pos1 (one global atomic per column per block) ----
    __syncthreads();
    atomicMax(&pos1e[b * N_ + jg0 + tid], sCol[tid]);
}

// ---------------- pass 2: stream u8 neg, masked mins vs pos0/pos1 ----------------
// grid: (N/16 row-stripes, B). Each block owns 16 full rows -> mn0 plain store.
__global__ __launch_bounds__(256) void neg_scan_k(const unsigned char* __restrict__ neg,
                                                  const unsigned* __restrict__ pos0e,
                                                  const unsigned* __restrict__ pos1e,
                                                  unsigned* __restrict__ mn0e,
                                                  unsigned* __restrict__ mn1e) {
    __shared__ float sP0[16];
    __shared__ float sR[16][4];
    const int b = blockIdx.y;
    const int i0 = blockIdx.x * 16;
    const int tid = threadIdx.x;
    const int w = tid >> 6;
    const int lane = tid & 63;
    if (tid < 16) sP0[tid] = dec_f(pos0e[b * N_ + i0 + tid]);
    float p1[16], cm[16];
#pragma unroll
    for (int k = 0; k < 16; ++k) {
        p1[k] = dec_f(pos1e[b * N_ + tid * 16 + k]);
        cm[k] = BIGV_;
    }
    __syncthreads();
    const unsigned char* nb = neg + ((size_t)b * N_ + i0) * N_;
    for (int r = 0; r < 16; ++r) {
        float p0 = sP0[r];
        float rmin = BIGV_;
        uint4 v = *(const uint4*)&nb[(size_t)r * N_ + tid * 16];
        unsigned wd[4] = {v.x, v.y, v.z, v.w};
#pragma unroll
        for (int k = 0; k < 16; ++k) {
            unsigned qv = (wd[k >> 2] >> ((k & 3) * 8)) & 0xFF;
            float ng = (qv == 255u) ? MAXD_ : (float)qv * QINV;
            float c0 = (ng > p0 && ng < p0 + MARGIN_) ? ng : BIGV_;
            rmin = fminf(rmin, c0);
            float pv = p1[k];
            float c1 = (ng > pv && ng < pv + MARGIN_) ? ng : BIGV_;
            cm[k] = fminf(cm[k], c1);
        }
#pragma unroll
        for (int m = 1; m < 64; m <<= 1) rmin = fminf(rmin, __shfl_xor(rmin, m, 64));
        if (lane == 0) sR[r][w] = rmin;
    }
    __syncthreads();
    if (tid < 16) {
        float m = fminf(fminf(sR[tid][0], sR[tid][1]), fminf(sR[tid][2], sR[tid][3]));
        mn0e[b * N_ + i0 + tid] = enc_f(m);   // exclusive owner of these rows
    }
#pragma unroll
    for (int k = 0; k < 16; ++k) {
        float v2 = cm[k];
        if (v2 < BIGV_)   // most lanes skip: init already holds +inf
            atomicMin(&mn1e[b * N_ + tid * 16 + k], enc_f(v2));
    }
}

// ---------------- final reduce: 2*B*N (pos, mn) pairs -> 3 outputs ----------------
__global__ __launch_bounds__(1024) void reduce_k(const unsigned* __restrict__ pose,
                                                 const unsigned* __restrict__ mne,
                                                 float* __restrict__ out) {
    int tid = threadIdx.x;
    float sum = 0.0f, cnt = 0.0f, hp = -BIGV_, hn = BIGV_;
    for (int idx = tid; idx < 2 * B_ * N_; idx += 1024) {
        float pos = dec_f(pose[idx]);
        float mn = dec_f(mne[idx]);
        bool valid = (pos > 0.0f) && (mn < 1.0e8f);
        if (valid) {
            sum += fmaxf(pos - mn + 1.0f, 0.0f);
            cnt += 1.0f;
            hp = fmaxf(hp, pos);
            hn = fminf(hn, mn);
        }
    }
#pragma unroll
    for (int m = 1; m < 64; m <<= 1) {
        sum += __shfl_xor(sum, m, 64);
        cnt += __shfl_xor(cnt, m, 64);
        hp = fmaxf(hp, __shfl_xor(hp, m, 64));
        hn = fminf(hn, __shfl_xor(hn, m, 64));
    }
    __shared__ float ssum[16], scnt[16], shp[16], shn[16];
    int wv = tid >> 6;
    if ((tid & 63) == 0) { ssum[wv] = sum; scnt[wv] = cnt; shp[wv] = hp; shn[wv] = hn; }
    __syncthreads();
    if (tid == 0) {
        float S = 0.f, C = 0.f, P = -BIGV_, M = BIGV_;
#pragma unroll
        for (int i = 0; i < 16; ++i) {
            S += ssum[i]; C += scnt[i];
            P = fmaxf(P, shp[i]); M = fminf(M, shn[i]);
        }
        out[0] = S / fmaxf(C, 1.0f);
        out[1] = P;
        out[2] = M;
    }
}

extern "C" void kernel_launch(void* const* d_in, const int* in_sizes, int n_in,
                              void* d_out, int out_size, void* d_ws, size_t ws_size,
                              hipStream_t stream) {
    const float* desc0 = (const float*)d_in[0];
    const float* desc1 = (const float*)d_in[1];
    const float* mat = (const float*)d_in[2];
    float* out = (float*)d_out;

    // ws layout (16B-aligned segments):
    // pos (2*B*N u32) | mns (2*B*N u32) | At bf16 | Bt bf16 | mu ushort | neg u8
    unsigned* pos = (unsigned*)d_ws;
    unsigned* mns = pos + 2 * B_ * N_;
    __hip_bfloat16* at = (__hip_bfloat16*)(mns + 2 * B_ * N_);
    __hip_bfloat16* bt = at + (size_t)B_ * N_ * D_;
    unsigned short* mu = (unsigned short*)(bt + (size_t)B_ * N_ * D_);
    unsigned char* neg = (unsigned char*)(mu + (size_t)B_ * N_ * 512);

    transpose_k<<<dim3(N_ / 64, D_ / 64, 2 * B_), dim3(64, 4), 0, stream>>>(desc0, desc1, at, bt);
    mask_k<<<dim3(N_ * 512 / 256, B_), 256, 0, stream>>>(mat, mu, pos);
    gemm_k<<<dim3(N_ / 512, N_ / 256, B_), 512, 0, stream>>>(
        at, bt, mu, pos, pos + B_ * N_, neg);
    neg_scan_k<<<dim3(N_ / 16, B_), 256, 0, stream>>>(
        neg, pos, pos + B_ * N_, mns, mns + B_ * N_);
    reduce_k<<<1, 1024, 0, stream>>>(pos, mns, out);
}

// Round 7
// 510.553 us; speedup vs baseline: 1.2223x; 1.2223x over previous
//
#include <hip/hip_runtime.h>
#include <hip/hip_bf16.h>
#include <cstdint>
#include <cstddef>

#define B_ 4
#define D_ 256
#define N_ 4096
#define N1 4097
#define MARGIN_ 0.5f
#define MAXD_ 10000.0f
#define BIGV_ 1000000000.0f
#define QSCALE 63.5f
#define QINV (4.0f / 254.0f)

typedef short s8v __attribute__((ext_vector_type(8)));
typedef float f4v __attribute__((ext_vector_type(4)));

// Order-preserving float <-> uint encoding so atomicMax/atomicMin on uint == on float.
__device__ __forceinline__ unsigned enc_f(float f) {
    unsigned u = __float_as_uint(f);
    return (u & 0x80000000u) ? ~u : (u | 0x80000000u);
}
__device__ __forceinline__ float dec_f(unsigned e) {
    return (e & 0x80000000u) ? __uint_as_float(e & 0x7FFFFFFFu) : __uint_as_float(~e);
}

__device__ __forceinline__ void async_copy16(__hip_bfloat16* lds, const __hip_bfloat16* g) {
    __builtin_amdgcn_global_load_lds(
        (const __attribute__((address_space(1))) void*)g,
        (__attribute__((address_space(3))) void*)lds, 16, 0, 0);
}

// ---------------- transpose+convert: (B,D,N) f32 -> (B,N,D) bf16, both descs ----------------
__global__ __launch_bounds__(256) void transpose_k(const float* __restrict__ src0,
                                                   const float* __restrict__ src1,
                                                   __hip_bfloat16* __restrict__ dst0,
                                                   __hip_bfloat16* __restrict__ dst1) {
    __shared__ float tile[64][65];
    int z = blockIdx.z;
    int b = z & 3;
    const float* src = (z < 4) ? src0 : src1;
    __hip_bfloat16* dst = (z < 4) ? dst0 : dst1;
    int i0 = blockIdx.x * 64;   // n-dim
    int k0 = blockIdx.y * 64;   // d-dim
    int tx = threadIdx.x;       // 0..63
    int ty = threadIdx.y;       // 0..3
    const float* s = src + ((size_t)b * D_ + k0) * N_ + i0;
#pragma unroll
    for (int r = 0; r < 16; ++r) {
        int kk = ty + 4 * r;
        tile[kk][tx] = s[(size_t)kk * N_ + tx];
    }
    __syncthreads();
    __hip_bfloat16* d = dst + ((size_t)b * N_ + i0) * D_ + k0;
#pragma unroll
    for (int r = 0; r < 16; ++r) {
        int ii = ty + 4 * r;
        d[(size_t)ii * D_ + tx] = __float2bfloat16(tile[tx][ii]);
    }
}

// ---------------- mask precompute (+ init of pos/mn arrays) ----------------
// mu[b][i][g] (ushort): low byte = match bits for cols 8g..8g+7 (ov>0.3),
//                       high byte = unmatch bits (ov<=0).
__global__ __launch_bounds__(256) void mask_k(const float* __restrict__ mat,
                                              unsigned short* __restrict__ mu,
                                              unsigned* __restrict__ initp) {
    int b = blockIdx.y;
    size_t t = (size_t)blockIdx.x * 256 + threadIdx.x;   // ushort index within batch
    if (b == 0 && blockIdx.x < 256) {
        int i = blockIdx.x * 256 + threadIdx.x;
        initp[i] = (i < 2 * B_ * N_) ? 0u : 0xFFFFFFFFu;
    }
    int i = (int)(t >> 9);          // row
    int g = (int)(t & 511);         // 8-col group
    const float* row = mat + (size_t)b * N1 * N1 + (size_t)i * N1 + g * 8;
    unsigned m = 0, u = 0;
#pragma unroll
    for (int k = 0; k < 8; ++k) {
        float v = row[k];
        m |= (v > 0.3f ? 1u : 0u) << k;
        u |= (v <= 0.0f ? 1u : 0u) << k;
    }
    mu[(size_t)b * N_ * 512 + t] = (unsigned short)(m | (u << 8));
}

// ---------------- persistent-A GEMM: pos maxes + u8 neg materialization ----------------
// Block: 128 rows (i) x 1024 cols (j-span), 4 waves; wave-tile 32x64.
// A-fragments (full K=256) held in registers; B double-buffered through 2x32KB LDS.
// Column relabel: lane (q,r), reg nj -> j = jb + 4r + nj.
// pos1 accumulated in LDS (sCol, ds_max_u32), flushed ONCE per block at the end:
// the per-jt __syncthreads no longer drains any global atomics (the R2..R5
// serializer: 32 y-blocks x 256 atomics/jt on the same 64 L2 addresses).
__global__ __launch_bounds__(256, 2) void gemm_k(const __hip_bfloat16* __restrict__ At,
                                                 const __hip_bfloat16* __restrict__ Bt,
                                                 const unsigned short* __restrict__ mu,
                                                 unsigned* __restrict__ pos0e,
                                                 unsigned* __restrict__ pos1e,
                                                 unsigned char* __restrict__ neg) {
    __shared__ __align__(16) __hip_bfloat16 Bs[2][64 * 256];   // 64 KB total
    __shared__ unsigned sCol[1024];                            // pos1 partials (enc)

    const int b = blockIdx.z;
    const int i0 = blockIdx.y * 128;
    const int jg0 = blockIdx.x * 1024;
    const int tid = threadIdx.x;
    const int lane = tid & 63;
    const int w = tid >> 6;
    const int r = lane & 15;
    const int q = lane >> 4;
    const int rl2 = lane >> 5;      // 0..1 row within 2-row staging granule
    const int ss = lane & 31;       // 16B segment slot within row

    __hip_bfloat16* BsF = &Bs[0][0];
    const __hip_bfloat16* Ab = At + ((size_t)b * N_ + i0) * D_;

    // ---- stage all 128 A rows (64 KB, XOR-swizzled by row&7) into Bs[0..1] ----
#pragma unroll
    for (int c = 0; c < 16; ++c) {
        int g = w * 16 + c;
        int row = 2 * g + rl2;      // 0..127
        async_copy16(BsF + g * 512, Ab + (size_t)row * D_ + (ss ^ (row & 7)) * 8);
    }
#pragma unroll
    for (int c = tid; c < 1024; c += 256) sCol[c] = 0u;   // enc-space minimum
    __syncthreads();

    // ---- load this wave's A fragments into registers (kept for whole kernel) ----
    s8v af[2][8];
#pragma unroll
    for (int mi = 0; mi < 2; ++mi) {
        int row = w * 32 + mi * 16 + r;
#pragma unroll
        for (int s = 0; s < 8; ++s)
            af[mi][s] = *(const s8v*)(BsF + row * 256 + (((s * 4 + q) ^ (row & 7)) * 8));
    }
    __syncthreads();   // everyone done reading A before B overwrites the LDS

    // ---- stage B tile 0 (swizzle key (row>>2)&7 to match 4r+nj frag reads) ----
    {
        const __hip_bfloat16* Bb = Bt + ((size_t)b * N_ + jg0) * D_;
#pragma unroll
        for (int c = 0; c < 8; ++c) {
            int g = w * 8 + c;
            int row = 2 * g + rl2;  // 0..63
            async_copy16(&Bs[0][g * 512], Bb + (size_t)row * D_ + (ss ^ ((row >> 2) & 7)) * 8);
        }
    }

    const unsigned short* mub = mu + ((size_t)b * N_ + i0) * 512;
    unsigned char* negb = neg + ((size_t)b * N_ + i0) * (size_t)N_;
    const int shn = 4 * (r & 1);

    float rowmax[8];
#pragma unroll
    for (int t = 0; t < 8; ++t) rowmax[t] = -BIGV_;

    for (int jt = 0; jt < 16; ++jt) {
        const int d = jt & 1;
        __syncthreads();            // B[jt] staged (vmcnt drained); prior buf reads done
        if (jt < 15) {              // prefetch next j-subtile into other buffer
            const __hip_bfloat16* Bb = Bt + ((size_t)b * N_ + jg0 + (jt + 1) * 64) * D_;
#pragma unroll
            for (int c = 0; c < 8; ++c) {
                int g = w * 8 + c;
                int row = 2 * g + rl2;
                async_copy16(&Bs[d ^ 1][g * 512], Bb + (size_t)row * D_ + (ss ^ ((row >> 2) & 7)) * 8);
            }
        }

        f4v acc[2][4];
#pragma unroll
        for (int mi = 0; mi < 2; ++mi)
#pragma unroll
            for (int nj = 0; nj < 4; ++nj) acc[mi][nj] = (f4v){0.f, 0.f, 0.f, 0.f};

#pragma unroll
        for (int s = 0; s < 8; ++s) {
            s8v bf[4];
#pragma unroll
            for (int nj = 0; nj < 4; ++nj) {
                int rl = 4 * r + nj;
                bf[nj] = *(const s8v*)(&Bs[d][rl * 256 + (((s * 4 + q) ^ (r & 7)) * 8)]);
            }
#pragma unroll
            for (int mi = 0; mi < 2; ++mi)
#pragma unroll
                for (int nj = 0; nj < 4; ++nj)
                    acc[mi][nj] = __builtin_amdgcn_mfma_f32_16x16x32_bf16(af[mi][s], bf[nj], acc[mi][nj], 0, 0, 0);
        }

        // ---- epilogue for this 128x64 j-subtile ----
        const int jb = jg0 + jt * 64;
        float colmax[4] = {-BIGV_, -BIGV_, -BIGV_, -BIGV_};
#pragma unroll
        for (int mi = 0; mi < 2; ++mi) {
#pragma unroll
            for (int rr = 0; rr < 4; ++rr) {
                int il = w * 32 + mi * 16 + q * 4 + rr;
                unsigned v = mub[(size_t)il * 512 + (jb >> 3) + (r >> 1)];
                unsigned packed = 0;
#pragma unroll
                for (int nj = 0; nj < 4; ++nj) {
                    bool is_m = (v >> (shn + nj)) & 1;
                    bool is_u = (v >> (8 + shn + nj)) & 1;
                    float Dv = 2.0f - 2.0f * acc[mi][nj][rr];
                    float dp = is_m ? Dv : 0.0f;
                    rowmax[mi * 4 + rr] = fmaxf(rowmax[mi * 4 + rr], dp);
                    colmax[nj] = fmaxf(colmax[nj], dp);
                    unsigned qv = is_u
                        ? (unsigned)(fminf(fmaxf(Dv, 0.0f), 4.0f) * QSCALE + 0.5f)
                        : 255u;
                    packed |= qv << (nj * 8);
                }
                *(unsigned*)&negb[(size_t)il * N_ + jb + 4 * r] = packed;
            }
        }
        // fold 4 q-groups, then one LDS atomic per column (ds_max_u32, 2-way alias = free)
#pragma unroll
        for (int nj = 0; nj < 4; ++nj) {
            float vv = colmax[nj];
            vv = fmaxf(vv, __shfl_xor(vv, 16, 64));
            vv = fmaxf(vv, __shfl_xor(vv, 32, 64));
            if (q == 0) atomicMax(&sCol[jt * 64 + 4 * r + nj], enc_f(vv));
        }
    }

    // ---- row maxes -> pos0 (one global atomic per row per block, off the jt path) ----
#pragma unroll
    for (int t = 0; t < 8; ++t) {
        float vv = rowmax[t];
#pragma unroll
        for (int m = 1; m < 16; m <<= 1) vv = fmaxf(vv, __shfl_xor(vv, m, 64));
        if (r == 0) {
            int row = w * 32 + (t >> 2) * 16 + q * 4 + (t & 3);
            atomicMax(&pos0e[b * N_ + i0 + row], enc_f(vv));
        }
    }
    // ---- col maxes -> pos1 (one global atomic per column per block, at the very end) ----
    __syncthreads();
#pragma unroll
    for (int c = tid; c < 1024; c += 256)
        atomicMax(&pos1e[b * N_ + jg0 + c], sCol[c]);
}

// ---------------- pass 2: stream u8 neg, masked mins vs pos0/pos1 ----------------
// grid: (N/16 row-stripes, B). Each block owns 16 full rows -> mn0 plain store.
__global__ __launch_bounds__(256) void neg_scan_k(const unsigned char* __restrict__ neg,
                                                  const unsigned* __restrict__ pos0e,
                                                  const unsigned* __restrict__ pos1e,
                                                  unsigned* __restrict__ mn0e,
                                                  unsigned* __restrict__ mn1e) {
    __shared__ float sP0[16];
    __shared__ float sR[16][4];
    const int b = blockIdx.y;
    const int i0 = blockIdx.x * 16;
    const int tid = threadIdx.x;
    const int w = tid >> 6;
    const int lane = tid & 63;
    if (tid < 16) sP0[tid] = dec_f(pos0e[b * N_ + i0 + tid]);
    float p1[16], cm[16];
#pragma unroll
    for (int k = 0; k < 16; ++k) {
        p1[k] = dec_f(pos1e[b * N_ + tid * 16 + k]);
        cm[k] = BIGV_;
    }
    __syncthreads();
    const unsigned char* nb = neg + ((size_t)b * N_ + i0) * N_;
    for (int r = 0; r < 16; ++r) {
        float p0 = sP0[r];
        float rmin = BIGV_;
        uint4 v = *(const uint4*)&nb[(size_t)r * N_ + tid * 16];
        unsigned wd[4] = {v.x, v.y, v.z, v.w};
#pragma unroll
        for (int k = 0; k < 16; ++k) {
            unsigned qv = (wd[k >> 2] >> ((k & 3) * 8)) & 0xFF;
            float ng = (qv == 255u) ? MAXD_ : (float)qv * QINV;
            float c0 = (ng > p0 && ng < p0 + MARGIN_) ? ng : BIGV_;
            rmin = fminf(rmin, c0);
            float pv = p1[k];
            float c1 = (ng > pv && ng < pv + MARGIN_) ? ng : BIGV_;
            cm[k] = fminf(cm[k], c1);
        }
#pragma unroll
        for (int m = 1; m < 64; m <<= 1) rmin = fminf(rmin, __shfl_xor(rmin, m, 64));
        if (lane == 0) sR[r][w] = rmin;
    }
    __syncthreads();
    if (tid < 16) {
        float m = fminf(fminf(sR[tid][0], sR[tid][1]), fminf(sR[tid][2], sR[tid][3]));
        mn0e[b * N_ + i0 + tid] = enc_f(m);   // exclusive owner of these rows
    }
#pragma unroll
    for (int k = 0; k < 16; ++k) {
        float v2 = cm[k];
        if (v2 < BIGV_)   // most lanes skip: init already holds +inf
            atomicMin(&mn1e[b * N_ + tid * 16 + k], enc_f(v2));
    }
}

// ---------------- final reduce: 2*B*N (pos, mn) pairs -> 3 outputs ----------------
__global__ __launch_bounds__(1024) void reduce_k(const unsigned* __restrict__ pose,
                                                 const unsigned* __restrict__ mne,
                                                 float* __restrict__ out) {
    int tid = threadIdx.x;
    float sum = 0.0f, cnt = 0.0f, hp = -BIGV_, hn = BIGV_;
    for (int idx = tid; idx < 2 * B_ * N_; idx += 1024) {
        float pos = dec_f(pose[idx]);
        float mn = dec_f(mne[idx]);
        bool valid = (pos > 0.0f) && (mn < 1.0e8f);
        if (valid) {
            sum += fmaxf(pos - mn + 1.0f, 0.0f);
            cnt += 1.0f;
            hp = fmaxf(hp, pos);
            hn = fminf(hn, mn);
        }
    }
#pragma unroll
    for (int m = 1; m < 64; m <<= 1) {
        sum += __shfl_xor(sum, m, 64);
        cnt += __shfl_xor(cnt, m, 64);
        hp = fmaxf(hp, __shfl_xor(hp, m, 64));
        hn = fminf(hn, __shfl_xor(hn, m, 64));
    }
    __shared__ float ssum[16], scnt[16], shp[16], shn[16];
    int wv = tid >> 6;
    if ((tid & 63) == 0) { ssum[wv] = sum; scnt[wv] = cnt; shp[wv] = hp; shn[wv] = hn; }
    __syncthreads();
    if (tid == 0) {
        float S = 0.f, C = 0.f, P = -BIGV_, M = BIGV_;
#pragma unroll
        for (int i = 0; i < 16; ++i) {
            S += ssum[i]; C += scnt[i];
            P = fmaxf(P, shp[i]); M = fminf(M, shn[i]);
        }
        out[0] = S / fmaxf(C, 1.0f);
        out[1] = P;
        out[2] = M;
    }
}

extern "C" void kernel_launch(void* const* d_in, const int* in_sizes, int n_in,
                              void* d_out, int out_size, void* d_ws, size_t ws_size,
                              hipStream_t stream) {
    const float* desc0 = (const float*)d_in[0];
    const float* desc1 = (const float*)d_in[1];
    const float* mat = (const float*)d_in[2];
    float* out = (float*)d_out;

    // ws layout (16B-aligned segments):
    // pos (2*B*N u32) | mns (2*B*N u32) | At bf16 | Bt bf16 | mu ushort | neg u8
    unsigned* pos = (unsigned*)d_ws;
    unsigned* mns = pos + 2 * B_ * N_;
    __hip_bfloat16* at = (__hip_bfloat16*)(mns + 2 * B_ * N_);
    __hip_bfloat16* bt = at + (size_t)B_ * N_ * D_;
    unsigned short* mu = (unsigned short*)(bt + (size_t)B_ * N_ * D_);
    unsigned char* neg = (unsigned char*)(mu + (size_t)B_ * N_ * 512);

    transpose_k<<<dim3(N_ / 64, D_ / 64, 2 * B_), dim3(64, 4), 0, stream>>>(desc0, desc1, at, bt);
    mask_k<<<dim3(N_ * 512 / 256, B_), 256, 0, stream>>>(mat, mu, pos);
    gemm_k<<<dim3(N_ / 1024, N_ / 128, B_), 256, 0, stream>>>(
        at, bt, mu, pos, pos + B_ * N_, neg);
    neg_scan_k<<<dim3(N_ / 16, B_), 256, 0, stream>>>(
        neg, pos, pos + B_ * N_, mns, mns + B_ * N_);
    reduce_k<<<1, 1024, 0, stream>>>(pos, mns, out);
}

// Round 8
// 467.876 us; speedup vs baseline: 1.3338x; 1.0912x over previous
//
#include <hip/hip_runtime.h>
#include <hip/hip_bf16.h>
#include <cstdint>
#include <cstddef>

#define B_ 4
#define D_ 256
#define N_ 4096
#define N1 4097
#define MARGIN_ 0.5f
#define MAXD_ 10000.0f
#define BIGV_ 1000000000.0f
#define QSCALE 63.5f
#define QINV (4.0f / 254.0f)

typedef short s8v __attribute__((ext_vector_type(8)));
typedef float f4v __attribute__((ext_vector_type(4)));

// Order-preserving float <-> uint encoding so atomicMax/atomicMin on uint == on float.
__device__ __forceinline__ unsigned enc_f(float f) {
    unsigned u = __float_as_uint(f);
    return (u & 0x80000000u) ? ~u : (u | 0x80000000u);
}
__device__ __forceinline__ float dec_f(unsigned e) {
    return (e & 0x80000000u) ? __uint_as_float(e & 0x7FFFFFFFu) : __uint_as_float(~e);
}

__device__ __forceinline__ void async_copy16(__hip_bfloat16* lds, const __hip_bfloat16* g) {
    __builtin_amdgcn_global_load_lds(
        (const __attribute__((address_space(1))) void*)g,
        (__attribute__((address_space(3))) void*)lds, 16, 0, 0);
}

// ---------------- transpose+convert: (B,D,N) f32 -> (B,N,D) bf16, both descs ----------------
// Also initializes pos/mn arrays (z==0 slice: 256 blocks x 256 threads == 65536 words).
__global__ __launch_bounds__(256) void transpose_k(const float* __restrict__ src0,
                                                   const float* __restrict__ src1,
                                                   __hip_bfloat16* __restrict__ dst0,
                                                   __hip_bfloat16* __restrict__ dst1,
                                                   unsigned* __restrict__ initp) {
    __shared__ float tile[64][65];
    int z = blockIdx.z;
    int b = z & 3;
    const float* src = (z < 4) ? src0 : src1;
    __hip_bfloat16* dst = (z < 4) ? dst0 : dst1;
    int tid = threadIdx.y * 64 + threadIdx.x;
    if (z == 0) {
        int idx = (blockIdx.y * 64 + blockIdx.x) * 256 + tid;   // 0..65535
        initp[idx] = (idx < 2 * B_ * N_) ? 0u : 0xFFFFFFFFu;
    }
    int i0 = blockIdx.x * 64;   // n-dim
    int k0 = blockIdx.y * 64;   // d-dim
    int tx = threadIdx.x;       // 0..63
    int ty = threadIdx.y;       // 0..3
    const float* s = src + ((size_t)b * D_ + k0) * N_ + i0;
#pragma unroll
    for (int r = 0; r < 16; ++r) {
        int kk = ty + 4 * r;
        tile[kk][tx] = s[(size_t)kk * N_ + tx];
    }
    __syncthreads();
    __hip_bfloat16* d = dst + ((size_t)b * N_ + i0) * D_ + k0;
#pragma unroll
    for (int r = 0; r < 16; ++r) {
        int ii = ty + 4 * r;
        d[(size_t)ii * D_ + tx] = __float2bfloat16(tile[tx][ii]);
    }
}

// ---------------- persistent-A GEMM + inline mask + pos maxes + u8 neg ----------------
// Block: 128 rows (i) x 1024 cols (j-span), 4 waves; wave-tile 32x64.
// A-fragments (full K=256) in registers; B double-buffered through 2x32KB LDS.
// Column relabel: lane (q,r), reg nj -> j = jb + 4r + nj.
// mat is read directly in the epilogue (32 dword loads/thread/jt, issued right
// after the barrier -> hidden under the MFMA s-loop). pos1 accumulates in LDS
// (sCol), flushed once per block at the end (R7's fix for the atomic drain).
__global__ __launch_bounds__(256, 2) void gemm_k(const __hip_bfloat16* __restrict__ At,
                                                 const __hip_bfloat16* __restrict__ Bt,
                                                 const float* __restrict__ mat,
                                                 unsigned* __restrict__ pos0e,
                                                 unsigned* __restrict__ pos1e,
                                                 unsigned char* __restrict__ neg) {
    __shared__ __align__(16) __hip_bfloat16 Bs[2][64 * 256];   // 64 KB total
    __shared__ unsigned sCol[1024];                            // pos1 partials (enc)

    const int b = blockIdx.z;
    const int i0 = blockIdx.y * 128;
    const int jg0 = blockIdx.x * 1024;
    const int tid = threadIdx.x;
    const int lane = tid & 63;
    const int w = tid >> 6;
    const int r = lane & 15;
    const int q = lane >> 4;
    const int rl2 = lane >> 5;      // 0..1 row within 2-row staging granule
    const int ss = lane & 31;       // 16B segment slot within row

    __hip_bfloat16* BsF = &Bs[0][0];
    const __hip_bfloat16* Ab = At + ((size_t)b * N_ + i0) * D_;

    // ---- stage all 128 A rows (64 KB, XOR-swizzled by row&7) into Bs[0..1] ----
#pragma unroll
    for (int c = 0; c < 16; ++c) {
        int g = w * 16 + c;
        int row = 2 * g + rl2;      // 0..127
        async_copy16(BsF + g * 512, Ab + (size_t)row * D_ + (ss ^ (row & 7)) * 8);
    }
#pragma unroll
    for (int c = tid; c < 1024; c += 256) sCol[c] = 0u;   // enc-space minimum
    __syncthreads();

    // ---- load this wave's A fragments into registers (kept for whole kernel) ----
    s8v af[2][8];
#pragma unroll
    for (int mi = 0; mi < 2; ++mi) {
        int row = w * 32 + mi * 16 + r;
#pragma unroll
        for (int s = 0; s < 8; ++s)
            af[mi][s] = *(const s8v*)(BsF + row * 256 + (((s * 4 + q) ^ (row & 7)) * 8));
    }
    __syncthreads();   // everyone done reading A before B overwrites the LDS

    // ---- stage B tile 0 (swizzle key (row>>2)&7 to match 4r+nj frag reads) ----
    {
        const __hip_bfloat16* Bb = Bt + ((size_t)b * N_ + jg0) * D_;
#pragma unroll
        for (int c = 0; c < 8; ++c) {
            int g = w * 8 + c;
            int row = 2 * g + rl2;  // 0..63
            async_copy16(&Bs[0][g * 512], Bb + (size_t)row * D_ + (ss ^ ((row >> 2) & 7)) * 8);
        }
    }

    const float* matb = mat + (size_t)b * N1 * N1 + (size_t)i0 * N1;
    unsigned char* negb = neg + ((size_t)b * N_ + i0) * (size_t)N_;

    float rowmax[8];
#pragma unroll
    for (int t = 0; t < 8; ++t) rowmax[t] = -BIGV_;

    for (int jt = 0; jt < 16; ++jt) {
        const int d = jt & 1;
        const int jb = jg0 + jt * 64;
        __syncthreads();            // B[jt] staged (vmcnt drained); prior buf reads done

        // ---- issue ov loads for this jt (consumed after the s-loop -> hidden) ----
        float ovv[8][4];
#pragma unroll
        for (int mi = 0; mi < 2; ++mi)
#pragma unroll
            for (int rr = 0; rr < 4; ++rr) {
                int il = w * 32 + mi * 16 + q * 4 + rr;
                const float* mrow = matb + (size_t)il * N1 + jb + 4 * r;
#pragma unroll
                for (int nj = 0; nj < 4; ++nj)
                    ovv[mi * 4 + rr][nj] = mrow[nj];
            }

        if (jt < 15) {              // prefetch next j-subtile into other buffer
            const __hip_bfloat16* Bb = Bt + ((size_t)b * N_ + jb + 64) * D_;
#pragma unroll
            for (int c = 0; c < 8; ++c) {
                int g = w * 8 + c;
                int row = 2 * g + rl2;
                async_copy16(&Bs[d ^ 1][g * 512], Bb + (size_t)row * D_ + (ss ^ ((row >> 2) & 7)) * 8);
            }
        }

        f4v acc[2][4];
#pragma unroll
        for (int mi = 0; mi < 2; ++mi)
#pragma unroll
            for (int nj = 0; nj < 4; ++nj) acc[mi][nj] = (f4v){0.f, 0.f, 0.f, 0.f};

#pragma unroll
        for (int s = 0; s < 8; ++s) {
            s8v bf[4];
#pragma unroll
            for (int nj = 0; nj < 4; ++nj) {
                int rl = 4 * r + nj;
                bf[nj] = *(const s8v*)(&Bs[d][rl * 256 + (((s * 4 + q) ^ (r & 7)) * 8)]);
            }
#pragma unroll
            for (int mi = 0; mi < 2; ++mi)
#pragma unroll
                for (int nj = 0; nj < 4; ++nj)
                    acc[mi][nj] = __builtin_amdgcn_mfma_f32_16x16x32_bf16(af[mi][s], bf[nj], acc[mi][nj], 0, 0, 0);
        }

        // ---- epilogue for this 128x64 j-subtile (masks inline from ovv) ----
        float colmax[4] = {-BIGV_, -BIGV_, -BIGV_, -BIGV_};
#pragma unroll
        for (int mi = 0; mi < 2; ++mi) {
#pragma unroll
            for (int rr = 0; rr < 4; ++rr) {
                int il = w * 32 + mi * 16 + q * 4 + rr;
                unsigned packed = 0;
#pragma unroll
                for (int nj = 0; nj < 4; ++nj) {
                    float ov = ovv[mi * 4 + rr][nj];
                    float Dv = 2.0f - 2.0f * acc[mi][nj][rr];
                    float dp = (ov > 0.3f) ? Dv : 0.0f;
                    rowmax[mi * 4 + rr] = fmaxf(rowmax[mi * 4 + rr], dp);
                    colmax[nj] = fmaxf(colmax[nj], dp);
                    unsigned qv = (ov <= 0.0f)
                        ? (unsigned)(fminf(fmaxf(Dv, 0.0f), 4.0f) * QSCALE + 0.5f)
                        : 255u;
                    packed |= qv << (nj * 8);
                }
                *(unsigned*)&negb[(size_t)il * N_ + jb + 4 * r] = packed;
            }
        }
        // fold 4 q-groups, then one LDS atomic per column (ds_max_u32, 2-way alias = free)
#pragma unroll
        for (int nj = 0; nj < 4; ++nj) {
            float vv = colmax[nj];
            vv = fmaxf(vv, __shfl_xor(vv, 16, 64));
            vv = fmaxf(vv, __shfl_xor(vv, 32, 64));
            if (q == 0) atomicMax(&sCol[jt * 64 + 4 * r + nj], enc_f(vv));
        }
    }

    // ---- row maxes -> pos0 (one global atomic per row per block, off the jt path) ----
#pragma unroll
    for (int t = 0; t < 8; ++t) {
        float vv = rowmax[t];
#pragma unroll
        for (int m = 1; m < 16; m <<= 1) vv = fmaxf(vv, __shfl_xor(vv, m, 64));
        if (r == 0) {
            int row = w * 32 + (t >> 2) * 16 + q * 4 + (t & 3);
            atomicMax(&pos0e[b * N_ + i0 + row], enc_f(vv));
        }
    }
    // ---- col maxes -> pos1 (one global atomic per column per block, at the very end) ----
    __syncthreads();
#pragma unroll
    for (int c = tid; c < 1024; c += 256)
        atomicMax(&pos1e[b * N_ + jg0 + c], sCol[c]);
}

// ---------------- pass 2: stream u8 neg, masked mins vs pos0/pos1 ----------------
// grid: (N/16 row-stripes, B). Each block owns 16 full rows -> mn0 plain store.
__global__ __launch_bounds__(256) void neg_scan_k(const unsigned char* __restrict__ neg,
                                                  const unsigned* __restrict__ pos0e,
                                                  const unsigned* __restrict__ pos1e,
                                                  unsigned* __restrict__ mn0e,
                                                  unsigned* __restrict__ mn1e) {
    __shared__ float sP0[16];
    __shared__ float sR[16][4];
    const int b = blockIdx.y;
    const int i0 = blockIdx.x * 16;
    const int tid = threadIdx.x;
    const int w = tid >> 6;
    const int lane = tid & 63;
    if (tid < 16) sP0[tid] = dec_f(pos0e[b * N_ + i0 + tid]);
    float p1[16], cm[16];
#pragma unroll
    for (int k = 0; k < 16; ++k) {
        p1[k] = dec_f(pos1e[b * N_ + tid * 16 + k]);
        cm[k] = BIGV_;
    }
    __syncthreads();
    const unsigned char* nb = neg + ((size_t)b * N_ + i0) * N_;
    for (int r = 0; r < 16; ++r) {
        float p0 = sP0[r];
        float rmin = BIGV_;
        uint4 v = *(const uint4*)&nb[(size_t)r * N_ + tid * 16];
        unsigned wd[4] = {v.x, v.y, v.z, v.w};
#pragma unroll
        for (int k = 0; k < 16; ++k) {
            unsigned qv = (wd[k >> 2] >> ((k & 3) * 8)) & 0xFF;
            float ng = (qv == 255u) ? MAXD_ : (float)qv * QINV;
            float c0 = (ng > p0 && ng < p0 + MARGIN_) ? ng : BIGV_;
            rmin = fminf(rmin, c0);
            float pv = p1[k];
            float c1 = (ng > pv && ng < pv + MARGIN_) ? ng : BIGV_;
            cm[k] = fminf(cm[k], c1);
        }
#pragma unroll
        for (int m = 1; m < 64; m <<= 1) rmin = fminf(rmin, __shfl_xor(rmin, m, 64));
        if (lane == 0) sR[r][w] = rmin;
    }
    __syncthreads();
    if (tid < 16) {
        float m = fminf(fminf(sR[tid][0], sR[tid][1]), fminf(sR[tid][2], sR[tid][3]));
        mn0e[b * N_ + i0 + tid] = enc_f(m);   // exclusive owner of these rows
    }
#pragma unroll
    for (int k = 0; k < 16; ++k) {
        float v2 = cm[k];
        if (v2 < BIGV_)   // most lanes skip: init already holds +inf
            atomicMin(&mn1e[b * N_ + tid * 16 + k], enc_f(v2));
    }
}

// ---------------- final reduce: 2*B*N (pos, mn) pairs -> 3 outputs ----------------
__global__ __launch_bounds__(1024) void reduce_k(const unsigned* __restrict__ pose,
                                                 const unsigned* __restrict__ mne,
                                                 float* __restrict__ out) {
    int tid = threadIdx.x;
    float sum = 0.0f, cnt = 0.0f, hp = -BIGV_, hn = BIGV_;
    for (int idx = tid; idx < 2 * B_ * N_; idx += 1024) {
        float pos = dec_f(pose[idx]);
        float mn = dec_f(mne[idx]);
        bool valid = (pos > 0.0f) && (mn < 1.0e8f);
        if (valid) {
            sum += fmaxf(pos - mn + 1.0f, 0.0f);
            cnt += 1.0f;
            hp = fmaxf(hp, pos);
            hn = fminf(hn, mn);
        }
    }
#pragma unroll
    for (int m = 1; m < 64; m <<= 1) {
        sum += __shfl_xor(sum, m, 64);
        cnt += __shfl_xor(cnt, m, 64);
        hp = fmaxf(hp, __shfl_xor(hp, m, 64));
        hn = fminf(hn, __shfl_xor(hn, m, 64));
    }
    __shared__ float ssum[16], scnt[16], shp[16], shn[16];
    int wv = tid >> 6;
    if ((tid & 63) == 0) { ssum[wv] = sum; scnt[wv] = cnt; shp[wv] = hp; shn[wv] = hn; }
    __syncthreads();
    if (tid == 0) {
        float S = 0.f, C = 0.f, P = -BIGV_, M = BIGV_;
#pragma unroll
        for (int i = 0; i < 16; ++i) {
            S += ssum[i]; C += scnt[i];
            P = fmaxf(P, shp[i]); M = fminf(M, shn[i]);
        }
        out[0] = S / fmaxf(C, 1.0f);
        out[1] = P;
        out[2] = M;
    }
}

extern "C" void kernel_launch(void* const* d_in, const int* in_sizes, int n_in,
                              void* d_out, int out_size, void* d_ws, size_t ws_size,
                              hipStream_t stream) {
    const float* desc0 = (const float*)d_in[0];
    const float* desc1 = (const float*)d_in[1];
    const float* mat = (const float*)d_in[2];
    float* out = (float*)d_out;

    // ws layout (16B-aligned segments):
    // pos (2*B*N u32) | mns (2*B*N u32) | At bf16 | Bt bf16 | neg u8
    unsigned* pos = (unsigned*)d_ws;
    unsigned* mns = pos + 2 * B_ * N_;
    __hip_bfloat16* at = (__hip_bfloat16*)(mns + 2 * B_ * N_);
    __hip_bfloat16* bt = at + (size_t)B_ * N_ * D_;
    unsigned char* neg = (unsigned char*)(bt + (size_t)B_ * N_ * D_);

    transpose_k<<<dim3(N_ / 64, D_ / 64, 2 * B_), dim3(64, 4), 0, stream>>>(
        desc0, desc1, at, bt, pos);
    gemm_k<<<dim3(N_ / 1024, N_ / 128, B_), 256, 0, stream>>>(
        at, bt, mat, pos, pos + B_ * N_, neg);
    neg_scan_k<<<dim3(N_ / 16, B_), 256, 0, stream>>>(
        neg, pos, pos + B_ * N_, mns, mns + B_ * N_);
    reduce_k<<<1, 1024, 0, stream>>>(pos, mns, out);
}